// Round 12
// baseline (49.856 us; speedup 1.0000x reference)
//
#include <hip/hip_runtime.h>
#include <hip/hip_bf16.h>

constexpr int IN_DIM = 128;   // feature dim
constexpr int HID    = 256;
constexpr int A_     = 8;     // aspects
constexpr int D_     = 64;    // aspect dim
constexpr int PAD    = 128;   // padded-CSR max degree (deg ~ Poisson(32); P(>=128) ~ 1e-40)
constexpr int NBITW  = 1024;  // bitmap words (covers N <= 32768)

// ---------------------------------------------------------------------------
// K1 (1024 threads/block):
//   bid 0        : pair-node bitmap (LDS-local zeroing -> no global dep)
//   bid 1..8     : weight fold, aspect a = bid-1
//   bid 9..16    : zero cnt region
//   bid 17..     : colsum partials, 32 rows/block (pure stores)
__global__ __launch_bounds__(1024) void k1_all(
    const float* __restrict__ aspW, const float* __restrict__ attW,
    const float* __restrict__ mergeW, const float* __restrict__ b1,
    const float* __restrict__ attb, const float* __restrict__ W1,
    const float* __restrict__ feat, const int* __restrict__ pairsFlat,
    float* __restrict__ WS, float* __restrict__ WM,
    float* __restrict__ sb, float* __restrict__ mb,
    unsigned int* __restrict__ bitsG,
    ulonglong2* __restrict__ zbase, int n16,
    float* __restrict__ pb, int N, int nIdx) {
  __shared__ float smem[4096];  // 16KB, re-carved per role
  const int bid = blockIdx.x;
  const int t = threadIdx.x;

  if (bid == 0) {
    // ---- pair-node bitmap (zeroed in LDS; atomicOr dedupe not needed, OR is idempotent)
    unsigned int* bits = (unsigned int*)smem;
    if (t < NBITW) bits[t] = 0u;
    __syncthreads();
#pragma unroll
    for (int k = 0; k < 8; ++k) {
      int i = k * 1024 + t;
      if (i < nIdx) {
        int node = pairsFlat[i];
        atomicOr(&bits[node >> 5], 1u << (node & 31));
      }
    }
    __syncthreads();
    if (t < NBITW) bitsG[t] = bits[t];
    return;
  }
  if (bid <= A_) {
    // ---- weight fold (validated 1024-thread version)
    int a = bid - 1;
    float* psS = smem;          // [4][256] then [8][128]
    float* psM = smem + 1024;
    float* Us  = smem + 2048;
    float* Um  = smem + 2304;
    float* r1  = smem + 2560;
    float* r2  = smem + 2816;
    {
      int h = t & 255, dq = t >> 8;  // dq 0..3, 16 d's each
      float ss = 0.f, sm = 0.f;
      const float* ap = aspW + (size_t)(a * D_ + dq * 16) * HID + h;
#pragma unroll
      for (int d = 0; d < 16; ++d) {
        float w = ap[(size_t)d * HID];
        ss += attW[dq * 16 + d] * w;
        sm += mergeW[dq * 16 + d] * w;
      }
      psS[dq * 256 + h] = ss;
      psM[dq * 256 + h] = sm;
    }
    __syncthreads();
    if (t < HID) {
      float us = psS[t] + psS[256 + t] + psS[512 + t] + psS[768 + t];
      float um = psM[t] + psM[256 + t] + psM[512 + t] + psM[768 + t];
      Us[t] = us; Um[t] = um;
      float bv = b1[t];
      r1[t] = us * bv; r2[t] = um * bv;
    }
    __syncthreads();
    for (int ofs = 128; ofs > 0; ofs >>= 1) {
      if (t < ofs) { r1[t] += r1[t + ofs]; r2[t] += r2[t + ofs]; }
      __syncthreads();
    }
    if (t == 0) { sb[a] = r1[0] + attb[0]; mb[a] = r2[0]; }
    __syncthreads();
    {
      int j = t & 127, ch = t >> 7;  // ch 0..7, 32 k's each
      float ws = 0.f, wm = 0.f;
      const float* w1p = W1 + (size_t)(ch * 32) * IN_DIM + j;
      const float* usp = Us + ch * 32;
      const float* ump = Um + ch * 32;
#pragma unroll
      for (int k = 0; k < 32; ++k) {
        float w = w1p[(size_t)k * IN_DIM];
        ws += usp[k] * w;
        wm += ump[k] * w;
      }
      psS[ch * 128 + j] = ws;
      psM[ch * 128 + j] = wm;
    }
    __syncthreads();
    if (t < IN_DIM) {
      float ws = 0.f, wm = 0.f;
#pragma unroll
      for (int c = 0; c < 8; ++c) { ws += psS[c * 128 + t]; wm += psM[c * 128 + t]; }
      WS[a * IN_DIM + t] = ws;
      WM[a * IN_DIM + t] = wm;
    }
    return;
  }
  if (bid <= 16) {
    // ---- zero cnt region (80KB)
    ulonglong2 z; z.x = 0ull; z.y = 0ull;
    for (int i = (bid - 9) * 1024 + t; i < n16; i += 8 * 1024) zbase[i] = z;
    return;
  }
  // ---- colsum partial: 32 rows, pure stores
  {
    int cb = bid - 17;
    int rslot = t >> 5, c4 = t & 31;
    int row = cb * 32 + rslot;
    float4 acc = make_float4(0.f, 0.f, 0.f, 0.f);
    if (row < N) {
      float4 v = ((const float4*)feat)[(size_t)row * 32 + c4];
      acc = v;
    }
    ((float4*)smem)[rslot * 32 + c4] = acc;
    __syncthreads();
    if (t < IN_DIM) {
      float s = 0.f;
#pragma unroll 8
      for (int r = 0; r < 32; ++r) s += smem[r * IN_DIM + t];
      pb[(size_t)cb * IN_DIM + t] = s;
    }
  }
}

// ---------------------------------------------------------------------------
// K2: blocks 0..fillBlocks-1 = masked (bitmap) padded-CSR build;
//     blocks fillBlocks.. (32) = reduce pb columns -> colsum.
__global__ void k2_fill_colred(const int4* __restrict__ src4, const int4* __restrict__ dst4,
                               const unsigned int* __restrict__ bitsG, int* __restrict__ cnt,
                               int* __restrict__ esrc, int E4, int fillBlocks,
                               const float* __restrict__ pb, float* __restrict__ colsum,
                               int npart) {
  if ((int)blockIdx.x >= fillBlocks) {
    int rblk = (int)blockIdx.x - fillBlocks;  // 0..31, cols 4r..4r+3
    int t = threadIdx.x;
    float4 acc = make_float4(0.f, 0.f, 0.f, 0.f);
    for (int row = t; row < npart; row += 256) {
      float4 v = ((const float4*)(pb + (size_t)row * IN_DIM))[rblk];
      acc.x += v.x; acc.y += v.y; acc.z += v.z; acc.w += v.w;
    }
    __shared__ float4 red[256];
    red[t] = acc;
    __syncthreads();
    for (int ofs = 128; ofs > 0; ofs >>= 1) {
      if (t < ofs) {
        float4 o = red[t + ofs];
        red[t].x += o.x; red[t].y += o.y; red[t].z += o.z; red[t].w += o.w;
      }
      __syncthreads();
    }
    if (t == 0) ((float4*)colsum)[rblk] = red[0];
    return;
  }
  int e = blockIdx.x * blockDim.x + threadIdx.x;
  if (e >= E4) return;
  int4 d = dst4[e];
  int4 s = src4[e];
  if ((bitsG[d.x >> 5] >> (d.x & 31)) & 1u) { int p = atomicAdd(&cnt[d.x], 1); if (p < PAD) esrc[(size_t)d.x * PAD + p] = s.x; }
  if ((bitsG[d.y >> 5] >> (d.y & 31)) & 1u) { int p = atomicAdd(&cnt[d.y], 1); if (p < PAD) esrc[(size_t)d.y * PAD + p] = s.y; }
  if ((bitsG[d.z >> 5] >> (d.z & 31)) & 1u) { int p = atomicAdd(&cnt[d.z], 1); if (p < PAD) esrc[(size_t)d.z * PAD + p] = s.z; }
  if ((bitsG[d.w >> 5] >> (d.w & 31)) & 1u) { int p = atomicAdd(&cnt[d.w], 1); if (p < PAD) esrc[(size_t)d.w * PAD + p] = s.w; }
}

// ---------------------------------------------------------------------------
// K3: fused pull + pair head. One block (128 thr = 2 waves) per pair;
//     wave `side` gathers node pairs[2b+side], computes its 16 dots, reduces;
//     thread 0 then computes softmax/merge/cat/log-softmax for the pair.
__global__ void __launch_bounds__(128) pairhead_k(
    const float* __restrict__ feat, const float* __restrict__ colsum,
    const int* __restrict__ cnt, const int* __restrict__ esrc,
    const int* __restrict__ pairsFlat, const float* __restrict__ WS,
    const float* __restrict__ WM, const float* __restrict__ sb,
    const float* __restrict__ mb, const float* __restrict__ catW,
    const float* __restrict__ catb, const float* __restrict__ mergeb,
    float* __restrict__ out, float invN) {
  __shared__ float pv[2][16];
  int b = blockIdx.x;
  int side = threadIdx.x >> 6;   // 0 or 1
  int lane = threadIdx.x & 63;   // 64 lanes, each owns 2 columns (float2)
  int d = pairsFlat[2 * b + side];
  int deg = cnt[d];
  const float2* F = (const float2*)feat;
  const int* es = esrc + (size_t)d * PAD;
  int n = deg < PAD ? deg : PAD;
  float2 acc = make_float2(0.f, 0.f);
  int i = 0;
  for (; i + 7 < n; i += 8) {
    float2 v0 = F[(size_t)es[i + 0] * 64 + lane];
    float2 v1 = F[(size_t)es[i + 1] * 64 + lane];
    float2 v2 = F[(size_t)es[i + 2] * 64 + lane];
    float2 v3 = F[(size_t)es[i + 3] * 64 + lane];
    float2 v4 = F[(size_t)es[i + 4] * 64 + lane];
    float2 v5 = F[(size_t)es[i + 5] * 64 + lane];
    float2 v6 = F[(size_t)es[i + 6] * 64 + lane];
    float2 v7 = F[(size_t)es[i + 7] * 64 + lane];
    acc.x += ((v0.x + v1.x) + (v2.x + v3.x)) + ((v4.x + v5.x) + (v6.x + v7.x));
    acc.y += ((v0.y + v1.y) + (v2.y + v3.y)) + ((v4.y + v5.y) + (v6.y + v7.y));
  }
  for (; i < n; ++i) {
    float2 v0 = F[(size_t)es[i] * 64 + lane];
    acc.x += v0.x;
    acc.y += v0.y;
  }
  float2 cm = ((const float2*)colsum)[lane];
  cm.x *= invN;
  cm.y *= invN;
  float2 fd = F[(size_t)d * 64 + lane];
  float2 x;
  if (deg > 0) {
    float inv = 1.0f / (float)deg;
    x.x = (fd.x + cm.x) * (acc.x * inv + cm.x);
    x.y = (fd.y + cm.y) * (acc.y * inv + cm.y);
  } else {
    x.x = 0.f;
    x.y = 0.f;
  }
  float v[16];
#pragma unroll
  for (int a = 0; a < A_; ++a) {
    float2 w = ((const float2*)WS)[a * 64 + lane];
    float2 u = ((const float2*)WM)[a * 64 + lane];
    v[a] = x.x * w.x + x.y * w.y;
    v[8 + a] = x.x * u.x + x.y * u.y;
  }
#pragma unroll
  for (int m = 32; m > 0; m >>= 1) {
#pragma unroll
    for (int k = 0; k < 16; ++k) v[k] += __shfl_xor(v[k], m, 64);
  }
  if (lane == 0) {
#pragma unroll
    for (int k = 0; k < 16; ++k) pv[side][k] = v[k];
  }
  __syncthreads();
  if (threadIdx.x == 0) {
    float mgb = mergeb[0];
    float p[2 * A_];
#pragma unroll
    for (int sd = 0; sd < 2; ++sd) {
      float s[A_], m[A_];
#pragma unroll
      for (int a = 0; a < A_; ++a) { s[a] = pv[sd][a] + sb[a]; m[a] = pv[sd][8 + a] + mb[a]; }
      float mx = s[0];
#pragma unroll
      for (int a = 1; a < A_; ++a) mx = fmaxf(mx, s[a]);
      float es_[A_], sum = 0.f;
#pragma unroll
      for (int a = 0; a < A_; ++a) { es_[a] = __expf(s[a] - mx); sum += es_[a]; }
      float rsum = 1.0f / sum;
#pragma unroll
      for (int a = 0; a < A_; ++a) p[sd * A_ + a] = es_[a] * rsum * m[a] + mgb;
    }
    float o0 = catb[0], o1 = catb[1];
#pragma unroll
    for (int k = 0; k < 2 * A_; ++k) {
      o0 += p[k] * catW[k];
      o1 += p[k] * catW[2 * A_ + k];
    }
    float mx = fmaxf(o0, o1);
    float lse = mx + logf(__expf(o0 - mx) + __expf(o1 - mx));
    out[b * 2 + 0] = o0 - lse;
    out[b * 2 + 1] = o1 - lse;
  }
}

// ---------------------------------------------------------------------------
extern "C" void kernel_launch(void* const* d_in, const int* in_sizes, int n_in,
                              void* d_out, int out_size, void* d_ws, size_t ws_size,
                              hipStream_t stream) {
  const float* feature = (const float*)d_in[0];
  const int*   src     = (const int*)d_in[1];
  const int*   dst     = (const int*)d_in[2];
  const int*   pairs   = (const int*)d_in[3];
  const float* W1      = (const float*)d_in[4];
  const float* b1      = (const float*)d_in[5];
  const float* aspW    = (const float*)d_in[6];
  const float* attW    = (const float*)d_in[7];
  const float* attb    = (const float*)d_in[8];
  const float* mergeW  = (const float*)d_in[9];
  const float* mergebp = (const float*)d_in[10];
  const float* catW    = (const float*)d_in[11];
  const float* catb    = (const float*)d_in[12];

  const int N = in_sizes[0] / IN_DIM;
  const int E = in_sizes[1];
  const int B = in_sizes[3] / 2;
  const int npart = (N + 31) / 32;                    // 625 colsum partials
  const int fillBlocks = (E / 4 + 255) / 256;         // 625
  const int E4 = E / 4;                               // E divisible by 4 (640000)

  // workspace layout (zeroed region = cnt only, 16B-aligned)
  char* ws = (char*)d_ws;
  size_t off_b = 0;
  int* cnt = (int*)(ws + off_b);        off_b += (size_t)N * sizeof(int);
  size_t zero_bytes = (off_b + 15) & ~(size_t)15;
  off_b = zero_bytes;
  unsigned int* bitsG = (unsigned int*)(ws + off_b); off_b += NBITW * sizeof(unsigned int);
  float* colsum = (float*)(ws + off_b); off_b += IN_DIM * sizeof(float);
  float* pb = (float*)(ws + off_b);     off_b += (size_t)npart * IN_DIM * sizeof(float);
  float* WS = (float*)(ws + off_b);     off_b += A_ * IN_DIM * sizeof(float);
  float* WM = (float*)(ws + off_b);     off_b += A_ * IN_DIM * sizeof(float);
  float* sb = (float*)(ws + off_b);     off_b += A_ * sizeof(float);
  float* mb = (float*)(ws + off_b);     off_b += A_ * sizeof(float);
  int* esrc = (int*)(ws + off_b);       off_b += (size_t)N * PAD * sizeof(int);

  k1_all<<<17 + npart, 1024, 0, stream>>>(
      aspW, attW, mergeW, b1, attb, W1, feature, pairs,
      WS, WM, sb, mb, bitsG,
      (ulonglong2*)d_ws, (int)(zero_bytes / 16), pb, N, 2 * B);
  k2_fill_colred<<<fillBlocks + 32, 256, 0, stream>>>(
      (const int4*)src, (const int4*)dst, bitsG, cnt, esrc, E4, fillBlocks,
      pb, colsum, npart);
  pairhead_k<<<B, 128, 0, stream>>>(feature, colsum, cnt, esrc, pairs, WS, WM,
                                    sb, mb, catW, catb, mergebp, (float*)d_out,
                                    1.0f / (float)N);
}

// Round 13
// 49.380 us; speedup vs baseline: 1.0096x; 1.0096x over previous
//
#include <hip/hip_runtime.h>
#include <hip/hip_bf16.h>

constexpr int IN_DIM = 128;   // feature dim
constexpr int HID    = 256;
constexpr int A_     = 8;     // aspects
constexpr int D_     = 64;    // aspect dim
constexpr int PAD    = 128;   // padded-CSR max degree (deg ~ Poisson(32); P(>=128) ~ 1e-40)
constexpr int NBITW  = 1024;  // bitmap words (covers N <= 32768)

// ---------------------------------------------------------------------------
// K1 (1024 threads/block):
//   bid 0        : pair-node bitmap + worklist (LDS-local zeroing -> no dep)
//   bid 1..8     : weight fold, aspect a = bid-1
//   bid 9..16    : zero cnt region
//   bid 17..     : colsum partials, 32 rows/block (pure stores)
__global__ __launch_bounds__(1024) void k1_all(
    const float* __restrict__ aspW, const float* __restrict__ attW,
    const float* __restrict__ mergeW, const float* __restrict__ b1,
    const float* __restrict__ attb, const float* __restrict__ W1,
    const float* __restrict__ feat, const int* __restrict__ pairsFlat,
    float* __restrict__ WS, float* __restrict__ WM,
    float* __restrict__ sb, float* __restrict__ mb,
    unsigned int* __restrict__ bitsG, int* __restrict__ wl, int* __restrict__ wlcnt,
    ulonglong2* __restrict__ zbase, int n16,
    float* __restrict__ pb, int N, int nIdx) {
  __shared__ float smem[4096];  // 16KB, re-carved per role
  const int bid = blockIdx.x;
  const int t = threadIdx.x;

  if (bid == 0) {
    // ---- pair-node bitmap + worklist (single block; bitmap zeroed in LDS)
    unsigned int* bits = (unsigned int*)smem;
    __shared__ int cnt_l;
    if (t < NBITW) bits[t] = 0u;
    if (t == 0) cnt_l = 0;
    __syncthreads();
#pragma unroll
    for (int k = 0; k < 8; ++k) {
      int i = k * 1024 + t;
      if (i < nIdx) {
        int node = pairsFlat[i];
        unsigned int m = 1u << (node & 31);
        unsigned int old = atomicOr(&bits[node >> 5], m);
        if ((old & m) == 0u) {
          int p = atomicAdd(&cnt_l, 1);
          wl[p] = node;
        }
      }
    }
    __syncthreads();
    if (t < NBITW) bitsG[t] = bits[t];
    if (t == 0) *wlcnt = cnt_l;
    return;
  }
  if (bid <= A_) {
    // ---- weight fold (validated 1024-thread version)
    int a = bid - 1;
    float* psS = smem;          // [4][256] then [8][128]
    float* psM = smem + 1024;
    float* Us  = smem + 2048;
    float* Um  = smem + 2304;
    float* r1  = smem + 2560;
    float* r2  = smem + 2816;
    {
      int h = t & 255, dq = t >> 8;  // dq 0..3, 16 d's each
      float ss = 0.f, sm = 0.f;
      const float* ap = aspW + (size_t)(a * D_ + dq * 16) * HID + h;
#pragma unroll
      for (int d = 0; d < 16; ++d) {
        float w = ap[(size_t)d * HID];
        ss += attW[dq * 16 + d] * w;
        sm += mergeW[dq * 16 + d] * w;
      }
      psS[dq * 256 + h] = ss;
      psM[dq * 256 + h] = sm;
    }
    __syncthreads();
    if (t < HID) {
      float us = psS[t] + psS[256 + t] + psS[512 + t] + psS[768 + t];
      float um = psM[t] + psM[256 + t] + psM[512 + t] + psM[768 + t];
      Us[t] = us; Um[t] = um;
      float bv = b1[t];
      r1[t] = us * bv; r2[t] = um * bv;
    }
    __syncthreads();
    for (int ofs = 128; ofs > 0; ofs >>= 1) {
      if (t < ofs) { r1[t] += r1[t + ofs]; r2[t] += r2[t + ofs]; }
      __syncthreads();
    }
    if (t == 0) { sb[a] = r1[0] + attb[0]; mb[a] = r2[0]; }
    __syncthreads();
    {
      int j = t & 127, ch = t >> 7;  // ch 0..7, 32 k's each
      float ws = 0.f, wm = 0.f;
      const float* w1p = W1 + (size_t)(ch * 32) * IN_DIM + j;
      const float* usp = Us + ch * 32;
      const float* ump = Um + ch * 32;
#pragma unroll
      for (int k = 0; k < 32; ++k) {
        float w = w1p[(size_t)k * IN_DIM];
        ws += usp[k] * w;
        wm += ump[k] * w;
      }
      psS[ch * 128 + j] = ws;
      psM[ch * 128 + j] = wm;
    }
    __syncthreads();
    if (t < IN_DIM) {
      float ws = 0.f, wm = 0.f;
#pragma unroll
      for (int c = 0; c < 8; ++c) { ws += psS[c * 128 + t]; wm += psM[c * 128 + t]; }
      WS[a * IN_DIM + t] = ws;
      WM[a * IN_DIM + t] = wm;
    }
    return;
  }
  if (bid <= 16) {
    // ---- zero cnt region (80KB)
    ulonglong2 z; z.x = 0ull; z.y = 0ull;
    for (int i = (bid - 9) * 1024 + t; i < n16; i += 8 * 1024) zbase[i] = z;
    return;
  }
  // ---- colsum partial: 32 rows, pure stores
  {
    int cb = bid - 17;
    int rslot = t >> 5, c4 = t & 31;
    int row = cb * 32 + rslot;
    float4 acc = make_float4(0.f, 0.f, 0.f, 0.f);
    if (row < N) {
      float4 v = ((const float4*)feat)[(size_t)row * 32 + c4];
      acc = v;
    }
    ((float4*)smem)[rslot * 32 + c4] = acc;
    __syncthreads();
    if (t < IN_DIM) {
      float s = 0.f;
#pragma unroll 8
      for (int r = 0; r < 32; ++r) s += smem[r * IN_DIM + t];
      pb[(size_t)cb * IN_DIM + t] = s;
    }
  }
}

// ---------------------------------------------------------------------------
// K2: blocks 0..fillBlocks-1 = masked (bitmap) padded-CSR build;
//     blocks fillBlocks.. (32) = reduce pb columns -> colsum.
__global__ void k2_fill_colred(const int4* __restrict__ src4, const int4* __restrict__ dst4,
                               const unsigned int* __restrict__ bitsG, int* __restrict__ cnt,
                               int* __restrict__ esrc, int E4, int fillBlocks,
                               const float* __restrict__ pb, float* __restrict__ colsum,
                               int npart) {
  if ((int)blockIdx.x >= fillBlocks) {
    int rblk = (int)blockIdx.x - fillBlocks;  // 0..31, cols 4r..4r+3
    int t = threadIdx.x;
    float4 acc = make_float4(0.f, 0.f, 0.f, 0.f);
    for (int row = t; row < npart; row += 256) {
      float4 v = ((const float4*)(pb + (size_t)row * IN_DIM))[rblk];
      acc.x += v.x; acc.y += v.y; acc.z += v.z; acc.w += v.w;
    }
    __shared__ float4 red[256];
    red[t] = acc;
    __syncthreads();
    for (int ofs = 128; ofs > 0; ofs >>= 1) {
      if (t < ofs) {
        float4 o = red[t + ofs];
        red[t].x += o.x; red[t].y += o.y; red[t].z += o.z; red[t].w += o.w;
      }
      __syncthreads();
    }
    if (t == 0) ((float4*)colsum)[rblk] = red[0];
    return;
  }
  int e = blockIdx.x * blockDim.x + threadIdx.x;
  if (e >= E4) return;
  int4 d = dst4[e];
  int4 s = src4[e];
  if ((bitsG[d.x >> 5] >> (d.x & 31)) & 1u) { int p = atomicAdd(&cnt[d.x], 1); if (p < PAD) esrc[(size_t)d.x * PAD + p] = s.x; }
  if ((bitsG[d.y >> 5] >> (d.y & 31)) & 1u) { int p = atomicAdd(&cnt[d.y], 1); if (p < PAD) esrc[(size_t)d.y * PAD + p] = s.y; }
  if ((bitsG[d.z >> 5] >> (d.z & 31)) & 1u) { int p = atomicAdd(&cnt[d.z], 1); if (p < PAD) esrc[(size_t)d.z * PAD + p] = s.z; }
  if ((bitsG[d.w >> 5] >> (d.w & 31)) & 1u) { int p = atomicAdd(&cnt[d.w], 1); if (p < PAD) esrc[(size_t)d.w * PAD + p] = s.w; }
}

// ---------------------------------------------------------------------------
// K3: pull + head dots, one wave per worklist node (validated R6 f32 path).
__global__ void __launch_bounds__(64) pull_k(
    const float* __restrict__ feat, const float* __restrict__ colsum,
    const int* __restrict__ cnt, const int* __restrict__ esrc,
    const int* __restrict__ wl, const int* __restrict__ wlcnt,
    const float* __restrict__ WS, const float* __restrict__ WM,
    float* __restrict__ nodevals, float invN) {
  int widx = blockIdx.x;
  if (widx >= *wlcnt) return;
  int d = wl[widx];
  int lane = threadIdx.x;  // 64 lanes, each owns 2 columns (float2)
  int deg = cnt[d];
  const float2* F = (const float2*)feat;
  const int* es = esrc + (size_t)d * PAD;
  int n = deg < PAD ? deg : PAD;
  float2 acc = make_float2(0.f, 0.f);
  int i = 0;
  for (; i + 7 < n; i += 8) {
    float2 v0 = F[(size_t)es[i + 0] * 64 + lane];
    float2 v1 = F[(size_t)es[i + 1] * 64 + lane];
    float2 v2 = F[(size_t)es[i + 2] * 64 + lane];
    float2 v3 = F[(size_t)es[i + 3] * 64 + lane];
    float2 v4 = F[(size_t)es[i + 4] * 64 + lane];
    float2 v5 = F[(size_t)es[i + 5] * 64 + lane];
    float2 v6 = F[(size_t)es[i + 6] * 64 + lane];
    float2 v7 = F[(size_t)es[i + 7] * 64 + lane];
    acc.x += ((v0.x + v1.x) + (v2.x + v3.x)) + ((v4.x + v5.x) + (v6.x + v7.x));
    acc.y += ((v0.y + v1.y) + (v2.y + v3.y)) + ((v4.y + v5.y) + (v6.y + v7.y));
  }
  for (; i < n; ++i) {
    float2 v0 = F[(size_t)es[i] * 64 + lane];
    acc.x += v0.x;
    acc.y += v0.y;
  }
  float2 cm = ((const float2*)colsum)[lane];
  cm.x *= invN;
  cm.y *= invN;
  float2 fd = F[(size_t)d * 64 + lane];
  float2 x;
  if (deg > 0) {
    float inv = 1.0f / (float)deg;
    x.x = (fd.x + cm.x) * (acc.x * inv + cm.x);
    x.y = (fd.y + cm.y) * (acc.y * inv + cm.y);
  } else {
    x.x = 0.f;
    x.y = 0.f;
  }
  float v[16];
#pragma unroll
  for (int a = 0; a < A_; ++a) {
    float2 w = ((const float2*)WS)[a * 64 + lane];
    float2 u = ((const float2*)WM)[a * 64 + lane];
    v[a] = x.x * w.x + x.y * w.y;
    v[8 + a] = x.x * u.x + x.y * u.y;
  }
#pragma unroll
  for (int m = 32; m > 0; m >>= 1) {
#pragma unroll
    for (int k = 0; k < 16; ++k) v[k] += __shfl_xor(v[k], m, 64);
  }
  if (lane == 0) {
#pragma unroll
    for (int k = 0; k < 16; ++k) nodevals[(size_t)d * 16 + k] = v[k];
  }
}

// ---------------------------------------------------------------------------
// K4: per-pair: 32 floats in, softmax over aspects, 2-class log-softmax out.
__global__ void pair_k(const int* __restrict__ pairs, const float* __restrict__ nodevals,
                       const float* __restrict__ sb, const float* __restrict__ mb,
                       const float* __restrict__ catW, const float* __restrict__ catb,
                       const float* __restrict__ mergeb, float* __restrict__ out, int B) {
  int b = blockIdx.x * blockDim.x + threadIdx.x;
  if (b >= B) return;
  float mgb = mergeb[0];
  float p[2 * A_];
  for (int side = 0; side < 2; ++side) {
    int node = pairs[b * 2 + side];
    const float4* nv = (const float4*)(nodevals + (size_t)node * 16);
    float4 q0 = nv[0], q1 = nv[1], q2 = nv[2], q3 = nv[3];
    float s[A_] = {q0.x, q0.y, q0.z, q0.w, q1.x, q1.y, q1.z, q1.w};
    float m[A_] = {q2.x, q2.y, q2.z, q2.w, q3.x, q3.y, q3.z, q3.w};
#pragma unroll
    for (int a = 0; a < A_; ++a) { s[a] += sb[a]; m[a] += mb[a]; }
    float mx = s[0];
#pragma unroll
    for (int a = 1; a < A_; ++a) mx = fmaxf(mx, s[a]);
    float es[A_], sum = 0.f;
#pragma unroll
    for (int a = 0; a < A_; ++a) { es[a] = __expf(s[a] - mx); sum += es[a]; }
    float rsum = 1.0f / sum;
#pragma unroll
    for (int a = 0; a < A_; ++a) p[side * A_ + a] = es[a] * rsum * m[a] + mgb;
  }
  float o0 = catb[0], o1 = catb[1];
#pragma unroll
  for (int k = 0; k < 2 * A_; ++k) {
    o0 += p[k] * catW[k];
    o1 += p[k] * catW[2 * A_ + k];
  }
  float mx = fmaxf(o0, o1);
  float lse = mx + logf(__expf(o0 - mx) + __expf(o1 - mx));
  out[b * 2 + 0] = o0 - lse;
  out[b * 2 + 1] = o1 - lse;
}

// ---------------------------------------------------------------------------
extern "C" void kernel_launch(void* const* d_in, const int* in_sizes, int n_in,
                              void* d_out, int out_size, void* d_ws, size_t ws_size,
                              hipStream_t stream) {
  const float* feature = (const float*)d_in[0];
  const int*   src     = (const int*)d_in[1];
  const int*   dst     = (const int*)d_in[2];
  const int*   pairs   = (const int*)d_in[3];
  const float* W1      = (const float*)d_in[4];
  const float* b1      = (const float*)d_in[5];
  const float* aspW    = (const float*)d_in[6];
  const float* attW    = (const float*)d_in[7];
  const float* attb    = (const float*)d_in[8];
  const float* mergeW  = (const float*)d_in[9];
  const float* mergebp = (const float*)d_in[10];
  const float* catW    = (const float*)d_in[11];
  const float* catb    = (const float*)d_in[12];

  const int N = in_sizes[0] / IN_DIM;
  const int E = in_sizes[1];
  const int B = in_sizes[3] / 2;
  const int npart = (N + 31) / 32;                    // 625 colsum partials
  const int fillBlocks = (E / 4 + 255) / 256;         // 625
  const int E4 = E / 4;                               // E divisible by 4 (640000)

  // workspace layout (zeroed region = cnt only, 16B-aligned)
  char* ws = (char*)d_ws;
  size_t off_b = 0;
  int* cnt = (int*)(ws + off_b);        off_b += (size_t)N * sizeof(int);
  size_t zero_bytes = (off_b + 15) & ~(size_t)15;
  off_b = zero_bytes;
  unsigned int* bitsG = (unsigned int*)(ws + off_b); off_b += NBITW * sizeof(unsigned int);
  int* wlcnt = (int*)(ws + off_b);      off_b += 4 * sizeof(int);
  int* wl = (int*)(ws + off_b);         off_b += (size_t)(2 * B) * sizeof(int);
  float* colsum = (float*)(ws + off_b); off_b += IN_DIM * sizeof(float);
  float* pb = (float*)(ws + off_b);     off_b += (size_t)npart * IN_DIM * sizeof(float);
  float* WS = (float*)(ws + off_b);     off_b += A_ * IN_DIM * sizeof(float);
  float* WM = (float*)(ws + off_b);     off_b += A_ * IN_DIM * sizeof(float);
  float* sb = (float*)(ws + off_b);     off_b += A_ * sizeof(float);
  float* mb = (float*)(ws + off_b);     off_b += A_ * sizeof(float);
  float* nodevals = (float*)(ws + off_b); off_b += (size_t)N * 16 * sizeof(float);
  int* esrc = (int*)(ws + off_b);       off_b += (size_t)N * PAD * sizeof(int);

  k1_all<<<17 + npart, 1024, 0, stream>>>(
      aspW, attW, mergeW, b1, attb, W1, feature, pairs,
      WS, WM, sb, mb, bitsG, wl, wlcnt,
      (ulonglong2*)d_ws, (int)(zero_bytes / 16), pb, N, 2 * B);
  k2_fill_colred<<<fillBlocks + 32, 256, 0, stream>>>(
      (const int4*)src, (const int4*)dst, bitsG, cnt, esrc, E4, fillBlocks,
      pb, colsum, npart);
  pull_k<<<2 * B, 64, 0, stream>>>(feature, colsum, cnt, esrc, wl, wlcnt, WS, WM,
                                   nodevals, 1.0f / (float)N);
  pair_k<<<(B + 255) / 256, 256, 0, stream>>>(pairs, nodevals, sb, mb, catW, catb,
                                              mergebp, (float*)d_out, B);
}